// Round 5
// baseline (2133.130 us; speedup 1.0000x reference)
//
#include <hip/hip_runtime.h>
#include <hip/hip_bf16.h>

#define HDIM 128
#define NREL 16
#define NBASES 8
#define LDSPAD 136   // A-tile row stride in shorts (16B-aligned rows, 2-way alias = free)
#define OPAD 136     // outAcc row stride in floats (136 mod 32 = 8 -> uniform 2-way = free)
#define HB 128       // counting-sort scatter blocks

typedef short bf16x8 __attribute__((ext_vector_type(8)));
typedef short s16x4 __attribute__((ext_vector_type(4)));
typedef float f32x4 __attribute__((ext_vector_type(4)));

static __device__ __forceinline__ short f2bf(float x) {
    __hip_bfloat16 b = __float2bfloat16(x);
    return *(short*)&b;
}

// ---------------- weight prep (fp32 in -> bf16 out) ----------------
// wt[r][o][i] = W_r[i][o] = sum_b wcomp[r][b] * basis[b][i][o]   (slots 0..15)
__global__ void compute_wt(const float* __restrict__ basis,
                           const float* __restrict__ wcomp,
                           short* __restrict__ wt) {
    int ro = blockIdx.x;
    int r = ro >> 7, o = ro & 127;
    int i = threadIdx.x;
    float acc = 0.f;
#pragma unroll
    for (int b = 0; b < NBASES; ++b)
        acc += wcomp[r * NBASES + b] * basis[(b * HDIM + i) * HDIM + o];
    wt[(size_t)(r * HDIM + o) * HDIM + i] = f2bf(acc);
}

// slot 16: lwT[o][i] = loop_w[i][o]
__global__ void transposeLW(const float* __restrict__ in, short* __restrict__ out) {
    int o = blockIdx.x, i = threadIdx.x;
    out[o * HDIM + i] = f2bf(in[i * HDIM + o]);
}

__global__ void cast_bf16(const float* __restrict__ in, short* __restrict__ out, int n4) {
    for (int i = blockIdx.x * blockDim.x + threadIdx.x; i < n4; i += gridDim.x * blockDim.x) {
        f32x4 v = ((const f32x4*)in)[i];
        s16x4 o;
#pragma unroll
        for (int j = 0; j < 4; ++j) o[j] = f2bf(v[j]);
        ((s16x4*)out)[i] = o;
    }
}

// ---------------- counting sort by key = (dst>>7)*16 + rel ----------------
__global__ __launch_bounds__(256) void histB(const int* __restrict__ dst,
                                             const int* __restrict__ rel,
                                             int n, int chunk, int nb,
                                             int* __restrict__ blockCnt) {
    extern __shared__ int hsm[];
    int tid = threadIdx.x, b = blockIdx.x;
    for (int q = tid; q < nb; q += 256) hsm[q] = 0;
    __syncthreads();
    int lo = b * chunk, hi = min(n, lo + chunk);
    for (int e = lo + tid; e < hi; e += 256)
        atomicAdd(&hsm[(dst[e] >> 7) * NREL + rel[e]], 1);
    __syncthreads();
    for (int q = tid; q < nb; q += 256) blockCnt[(size_t)b * nb + q] = hsm[q];
}

// per-bucket within-bucket base for each scatter block + column totals
__global__ void scanA(const int* __restrict__ blockCnt, int* __restrict__ baseArr,
                      int* __restrict__ colsum, int nb) {
    int q = blockIdx.x * blockDim.x + threadIdx.x;
    if (q >= nb) return;
    int run = 0;
    for (int b = 0; b < HB; ++b) {
        int v = blockCnt[(size_t)b * nb + q];
        baseArr[(size_t)b * nb + q] = run;
        run += v;
    }
    colsum[q] = run;
}

// exclusive prefix over buckets -> bucketOff[0..nb]
__global__ __launch_bounds__(256) void scanB(const int* __restrict__ colsum,
                                             int* __restrict__ bucketOff, int nb) {
    __shared__ int part[256];
    int t = threadIdx.x;
    int per = (nb + 255) >> 8;
    int lo = t * per, hi = min(nb, lo + per);
    int s = 0;
    for (int q = lo; q < hi; ++q) s += colsum[q];
    part[t] = s;
    __syncthreads();
    if (t == 0) {
        int run = 0;
        for (int i = 0; i < 256; ++i) { int v = part[i]; part[i] = run; run += v; }
        bucketOff[nb] = run;
    }
    __syncthreads();
    int run = part[t];
    for (int q = lo; q < hi; ++q) { bucketOff[q] = run; run += colsum[q]; }
}

__global__ __launch_bounds__(256) void scatterB(const int* __restrict__ src,
                                                const int* __restrict__ dst,
                                                const int* __restrict__ rel,
                                                int n, int chunk, int nb,
                                                const int* __restrict__ bucketOff,
                                                const int* __restrict__ baseArr,
                                                int* __restrict__ src_s,
                                                int* __restrict__ dst_s) {
    extern __shared__ int cur[];
    int tid = threadIdx.x, b = blockIdx.x;
    for (int q = tid; q < nb; q += 256) cur[q] = bucketOff[q] + baseArr[(size_t)b * nb + q];
    __syncthreads();
    int lo = b * chunk, hi = min(n, lo + chunk);
    for (int e = lo + tid; e < hi; e += 256) {
        int d = dst[e];
        int key = (d >> 7) * NREL + rel[e];
        int p = atomicAdd(&cur[key], 1);
        src_s[p] = src[e];
        dst_s[p] = d;
    }
}

// ---------------- fused per-dst-tile GEMM+aggregate+self+bias+relu ----------------
// Block t owns output rows [t*128, t*128+128). LDS fp32 accumulator; no global atomics.
template<int FINAL>
__global__ __launch_bounds__(256) void node_gemm(
    const short* __restrict__ h,     // bf16 [M,128]
    const short* __restrict__ wt,    // bf16 [17][o][i]  (16 = loop_w)
    const float* __restrict__ bias,  // fp32 [128]
    const int* __restrict__ bucketOff,
    const int* __restrict__ src_s, const int* __restrict__ dst_s,
    void* __restrict__ outv, int M) {
    __shared__ float outAcc[128 * OPAD];   // 69.6 KB
    __shared__ short As[128 * LDSPAD];     // 34.8 KB
    __shared__ int dloc[128];
    int t = blockIdx.x;
    int row0 = t << 7;
    int tid = threadIdx.x;
    int wave = tid >> 6, lane = tid & 63;
    int mq = (wave & 1) * 64, nq = (wave >> 1) * 64;
    int lr = lane & 15, quad = lane >> 4;
    int lane16 = tid & 15, rsub = tid >> 4;

    // init outAcc rows to bias
    for (int idx = tid; idx < 128 * 32; idx += 256) {
        int row = idx >> 5, n0 = (idx & 31) << 2;
        *(f32x4*)&outAcc[row * OPAD + n0] = *(const f32x4*)&bias[n0];
    }
    __syncthreads();

    for (int r = 0; r <= NREL; ++r) {
        int lo, hi;
        if (r < NREL) { lo = bucketOff[t * NREL + r]; hi = bucketOff[t * NREL + r + 1]; }
        else { lo = row0; hi = min(row0 + 128, M); }   // self-loop rows
        if (lo >= hi) continue;
        const short* wr = wt + (size_t)r * HDIM * HDIM;
        bf16x8 b[4][4];
#pragma unroll
        for (int kk = 0; kk < 4; ++kk)
#pragma unroll
            for (int ni = 0; ni < 4; ++ni)
                b[kk][ni] = *(const bf16x8*)(wr + (nq + ni * 16 + lr) * HDIM + kk * 32 + quad * 8);

        for (int e0 = lo; e0 < hi; e0 += 128) {
            // stage A (gathered src rows) + dst-local indices
#pragma unroll
            for (int p = 0; p < 8; ++p) {
                int row = p * 16 + rsub;
                int e = e0 + row;
                bf16x8 va = (bf16x8)0;
                if (e < hi) {
                    int s = (r < NREL) ? src_s[e] : e;
                    va = *(const bf16x8*)(h + (size_t)s * HDIM + lane16 * 8);
                }
                *(bf16x8*)(As + row * LDSPAD + lane16 * 8) = va;
            }
            if (tid < 128) {
                int e = e0 + tid;
                dloc[tid] = (e < hi) ? ((r < NREL) ? dst_s[e] - row0 : e - row0) : -1;
            }
            __syncthreads();

            f32x4 acc[4][4] = {};
#pragma unroll
            for (int kk = 0; kk < 4; ++kk) {
                int kb = kk * 32 + quad * 8;
                bf16x8 a[4];
#pragma unroll
                for (int mi = 0; mi < 4; ++mi)
                    a[mi] = *(const bf16x8*)(As + (mq + mi * 16 + lr) * LDSPAD + kb);
#pragma unroll
                for (int mi = 0; mi < 4; ++mi)
#pragma unroll
                    for (int ni = 0; ni < 4; ++ni)
                        acc[mi][ni] = __builtin_amdgcn_mfma_f32_16x16x32_bf16(a[mi], b[kk][ni], acc[mi][ni], 0, 0, 0);
            }
            __syncthreads();   // As fully consumed before next chunk overwrites

            // scatter C fragments into LDS accumulator (ds_add_f32)
#pragma unroll
            for (int mi = 0; mi < 4; ++mi) {
#pragma unroll
                for (int reg = 0; reg < 4; ++reg) {
                    int m = mq + mi * 16 + quad * 4 + reg;
                    int d = dloc[m];
                    if (d >= 0) {
#pragma unroll
                        for (int ni = 0; ni < 4; ++ni)
                            atomicAdd(&outAcc[d * OPAD + nq + ni * 16 + lr], acc[mi][ni][reg]);
                    }
                }
            }
        }
    }
    __syncthreads();

    // epilogue: relu + store (bf16 intermediate or fp32 final)
    for (int idx = tid; idx < 128 * 32; idx += 256) {
        int row = idx >> 5, n0 = (idx & 31) << 2;
        int g = row0 + row;
        if (g >= M) continue;
        f32x4 v = *(f32x4*)&outAcc[row * OPAD + n0];
        f32x4 o;
#pragma unroll
        for (int j = 0; j < 4; ++j) o[j] = v[j] > 0.f ? v[j] : 0.f;
        if (FINAL) {
            *(f32x4*)((float*)outv + (size_t)g * HDIM + n0) = o;
        } else {
            s16x4 ob;
#pragma unroll
            for (int j = 0; j < 4; ++j) ob[j] = f2bf(o[j]);
            *(s16x4*)((short*)outv + (size_t)g * HDIM + n0) = ob;
        }
    }
}

extern "C" void kernel_launch(void* const* d_in, const int* in_sizes, int n_in,
                              void* d_out, int out_size, void* d_ws, size_t ws_size,
                              hipStream_t stream) {
    const float* emb    = (const float*)d_in[0];
    const float* basis1 = (const float*)d_in[1];
    const float* wc1    = (const float*)d_in[2];
    const float* lw1    = (const float*)d_in[3];
    const float* bias1  = (const float*)d_in[4];
    const float* basis2 = (const float*)d_in[5];
    const float* wc2    = (const float*)d_in[6];
    const float* lw2    = (const float*)d_in[7];
    const float* bias2  = (const float*)d_in[8];
    const int* src = (const int*)d_in[9];
    const int* dst = (const int*)d_in[10];
    const int* rel = (const int*)d_in[11];

    int n_ent = in_sizes[0] / HDIM;
    int n_edges = in_sizes[9];
    int ntiles = (n_ent + 127) / 128;
    int nb = ntiles * NREL;                 // buckets

    char* ws = (char*)d_ws;
    short* wtA = (short*)ws;                              // 17*16384*2 = 557 KB
    short* wtB = wtA + 17 * HDIM * HDIM;                  // 557 KB
    short* h0  = wtB + 17 * HDIM * HDIM;                  // 12.8 MB bf16
    short* h1  = h0 + (size_t)n_ent * HDIM;               // 12.8 MB bf16
    int* src_s = (int*)(h1 + (size_t)n_ent * HDIM);       // 3.2 MB
    int* dst_s = src_s + n_edges;                         // 3.2 MB
    int* blockCnt = dst_s + n_edges;                      // HB*nb*4 = 3.2 MB
    int* baseArr  = blockCnt + (size_t)HB * nb;           // 3.2 MB
    int* bucketOff = baseArr + (size_t)HB * nb;           // (nb+1)*4
    int* colsum    = bucketOff + nb + 1;                  // nb*4

    int chunk = (n_edges + HB - 1) / HB;

    compute_wt<<<NREL * HDIM, HDIM, 0, stream>>>(basis1, wc1, wtA);
    compute_wt<<<NREL * HDIM, HDIM, 0, stream>>>(basis2, wc2, wtB);
    transposeLW<<<HDIM, HDIM, 0, stream>>>(lw1, wtA + 16 * HDIM * HDIM);
    transposeLW<<<HDIM, HDIM, 0, stream>>>(lw2, wtB + 16 * HDIM * HDIM);
    cast_bf16<<<512, 256, 0, stream>>>(emb, h0, n_ent * HDIM / 4);

    histB<<<HB, 256, nb * 4, stream>>>(dst, rel, n_edges, chunk, nb, blockCnt);
    scanA<<<(nb + 255) / 256, 256, 0, stream>>>(blockCnt, baseArr, colsum, nb);
    scanB<<<1, 256, 0, stream>>>(colsum, bucketOff, nb);
    scatterB<<<HB, 256, nb * 4, stream>>>(src, dst, rel, n_edges, chunk, nb,
                                          bucketOff, baseArr, src_s, dst_s);

    node_gemm<0><<<ntiles, 256, 0, stream>>>(h0, wtA, bias1, bucketOff, src_s, dst_s, h1, n_ent);
    node_gemm<1><<<ntiles, 256, 0, stream>>>(h1, wtB, bias2, bucketOff, src_s, dst_s, d_out, n_ent);
}

// Round 7
// 1807.483 us; speedup vs baseline: 1.1802x; 1.1802x over previous
//
#include <hip/hip_runtime.h>
#include <hip/hip_bf16.h>

#define HDIM 128
#define NREL 16
#define NBASES 8
#define TROWS 64     // dst-tile rows per block
#define LDSPAD 136   // A-tile row stride in shorts (16B-aligned rows, 2-way alias = free)
#define OPAD 132     // outAcc row stride in floats
#define HB 128       // counting-sort scatter blocks

typedef short bf16x8 __attribute__((ext_vector_type(8)));
typedef short s16x4 __attribute__((ext_vector_type(4)));
typedef float f32x4 __attribute__((ext_vector_type(4)));

static __device__ __forceinline__ short f2bf(float x) {
    __hip_bfloat16 b = __float2bfloat16(x);
    return *(short*)&b;
}

// ---------------- weight prep (fp32 in -> bf16 out) ----------------
// wt[r][o][i] = W_r[i][o] = sum_b wcomp[r][b] * basis[b][i][o]   (slots 0..15)
__global__ void compute_wt(const float* __restrict__ basis,
                           const float* __restrict__ wcomp,
                           short* __restrict__ wt) {
    int ro = blockIdx.x;
    int r = ro >> 7, o = ro & 127;
    int i = threadIdx.x;
    float acc = 0.f;
#pragma unroll
    for (int b = 0; b < NBASES; ++b)
        acc += wcomp[r * NBASES + b] * basis[(b * HDIM + i) * HDIM + o];
    wt[(size_t)(r * HDIM + o) * HDIM + i] = f2bf(acc);
}

// slot 16: lwT[o][i] = loop_w[i][o]
__global__ void transposeLW(const float* __restrict__ in, short* __restrict__ out) {
    int o = blockIdx.x, i = threadIdx.x;
    out[o * HDIM + i] = f2bf(in[i * HDIM + o]);
}

__global__ void cast_bf16(const float* __restrict__ in, short* __restrict__ out, int n4) {
    for (int i = blockIdx.x * blockDim.x + threadIdx.x; i < n4; i += gridDim.x * blockDim.x) {
        f32x4 v = ((const f32x4*)in)[i];
        s16x4 o;
#pragma unroll
        for (int j = 0; j < 4; ++j) o[j] = f2bf(v[j]);
        ((s16x4*)out)[i] = o;
    }
}

// ---------------- counting sort by key = (dst>>6)*16 + rel ----------------
__global__ __launch_bounds__(256) void histB(const int* __restrict__ dst,
                                             const int* __restrict__ rel,
                                             int n, int chunk, int nb,
                                             int* __restrict__ blockCnt) {
    extern __shared__ int hsm[];
    int tid = threadIdx.x, b = blockIdx.x;
    for (int q = tid; q < nb; q += 256) hsm[q] = 0;
    __syncthreads();
    int lo = b * chunk, hi = min(n, lo + chunk);
    for (int e = lo + tid; e < hi; e += 256)
        atomicAdd(&hsm[(dst[e] >> 6) * NREL + rel[e]], 1);
    __syncthreads();
    for (int q = tid; q < nb; q += 256) blockCnt[(size_t)b * nb + q] = hsm[q];
}

__global__ void scanA(const int* __restrict__ blockCnt, int* __restrict__ baseArr,
                      int* __restrict__ colsum, int nb) {
    int q = blockIdx.x * blockDim.x + threadIdx.x;
    if (q >= nb) return;
    int run = 0;
    for (int b = 0; b < HB; ++b) {
        int v = blockCnt[(size_t)b * nb + q];
        baseArr[(size_t)b * nb + q] = run;
        run += v;
    }
    colsum[q] = run;
}

__global__ __launch_bounds__(256) void scanB(const int* __restrict__ colsum,
                                             int* __restrict__ bucketOff, int nb) {
    __shared__ int part[256];
    int t = threadIdx.x;
    int per = (nb + 255) >> 8;
    int lo = t * per, hi = min(nb, lo + per);
    int s = 0;
    for (int q = lo; q < hi; ++q) s += colsum[q];
    part[t] = s;
    __syncthreads();
    if (t == 0) {
        int run = 0;
        for (int i = 0; i < 256; ++i) { int v = part[i]; part[i] = run; run += v; }
        bucketOff[nb] = run;
    }
    __syncthreads();
    int run = part[t];
    for (int q = lo; q < hi; ++q) { bucketOff[q] = run; run += colsum[q]; }
}

__global__ __launch_bounds__(256) void scatterB(const int* __restrict__ src,
                                                const int* __restrict__ dst,
                                                const int* __restrict__ rel,
                                                int n, int chunk, int nb,
                                                const int* __restrict__ bucketOff,
                                                const int* __restrict__ baseArr,
                                                int* __restrict__ src_s,
                                                int* __restrict__ dst_s) {
    extern __shared__ int cur[];
    int tid = threadIdx.x, b = blockIdx.x;
    for (int q = tid; q < nb; q += 256) cur[q] = bucketOff[q] + baseArr[(size_t)b * nb + q];
    __syncthreads();
    int lo = b * chunk, hi = min(n, lo + chunk);
    for (int e = lo + tid; e < hi; e += 256) {
        int d = dst[e];
        int key = (d >> 6) * NREL + rel[e];
        int p = atomicAdd(&cur[key], 1);
        src_s[p] = src[e];
        dst_s[p] = d;
    }
}

// ---------------- fused per-dst-tile (64 rows) GEMM+aggregate+self+bias+relu ----------------
// Block t owns output rows [t*64, t*64+64). LDS fp32 accumulator; no global atomics.
// dloc is read into registers (dreg) BEFORE the barrier that releases the staging
// buffers — the scatter after that barrier touches only registers + outAcc, so the
// next chunk's staging cannot race it (round-6 bug fix).
template<int FINAL>
__global__ __launch_bounds__(256) void node_gemm(
    const short* __restrict__ h,     // bf16 [M,128]
    const short* __restrict__ wt,    // bf16 [17][o][i]  (16 = loop_w)
    const float* __restrict__ bias,  // fp32 [128]
    const int* __restrict__ bucketOff,
    const int* __restrict__ src_s, const int* __restrict__ dst_s,
    void* __restrict__ outv, int M) {
    __shared__ float outAcc[TROWS * OPAD];
    __shared__ short As[TROWS * LDSPAD];
    __shared__ int dloc[TROWS];
    int t = blockIdx.x;
    int row0 = t * TROWS;
    int tid = threadIdx.x;
    int wave = tid >> 6, lane = tid & 63;
    int nq = wave * 32;                    // each wave: 64 rows x 32 cols
    int lr = lane & 15, quad = lane >> 4;
    int lane16 = tid & 15, rsub = tid >> 4;

    // init outAcc rows to bias
    for (int idx = tid; idx < TROWS * 32; idx += 256) {
        int row = idx >> 5, n0 = (idx & 31) << 2;
        *(f32x4*)&outAcc[row * OPAD + n0] = *(const f32x4*)&bias[n0];
    }
    __syncthreads();

    for (int r = 0; r <= NREL; ++r) {
        int lo, hi;
        if (r < NREL) { lo = bucketOff[t * NREL + r]; hi = bucketOff[t * NREL + r + 1]; }
        else { lo = row0; hi = min(row0 + TROWS, M); }   // self-loop rows
        if (lo >= hi) continue;
        const short* wr = wt + (size_t)r * HDIM * HDIM;
        bf16x8 b[4][2];
#pragma unroll
        for (int kk = 0; kk < 4; ++kk)
#pragma unroll
            for (int ni = 0; ni < 2; ++ni)
                b[kk][ni] = *(const bf16x8*)(wr + (nq + ni * 16 + lr) * HDIM + kk * 32 + quad * 8);

        for (int e0 = lo; e0 < hi; e0 += TROWS) {
            // stage A (gathered src rows) + dst-local indices
#pragma unroll
            for (int p = 0; p < 4; ++p) {
                int row = p * 16 + rsub;
                int e = e0 + row;
                bf16x8 va = (bf16x8)0;
                if (e < hi) {
                    int s = (r < NREL) ? src_s[e] : e;
                    va = *(const bf16x8*)(h + (size_t)s * HDIM + lane16 * 8);
                }
                *(bf16x8*)(As + row * LDSPAD + lane16 * 8) = va;
            }
            if (tid < TROWS) {
                int e = e0 + tid;
                dloc[tid] = (e < hi) ? ((r < NREL) ? dst_s[e] - row0 : e - row0) : -1;
            }
            __syncthreads();

            // pull dloc into registers BEFORE the releasing barrier (race fix)
            int dreg[4][4];
#pragma unroll
            for (int mi = 0; mi < 4; ++mi)
#pragma unroll
                for (int reg = 0; reg < 4; ++reg)
                    dreg[mi][reg] = dloc[mi * 16 + quad * 4 + reg];

            f32x4 acc[4][2] = {};
#pragma unroll
            for (int kk = 0; kk < 4; ++kk) {
                int kb = kk * 32 + quad * 8;
                bf16x8 a[4];
#pragma unroll
                for (int mi = 0; mi < 4; ++mi)
                    a[mi] = *(const bf16x8*)(As + (mi * 16 + lr) * LDSPAD + kb);
#pragma unroll
                for (int mi = 0; mi < 4; ++mi)
#pragma unroll
                    for (int ni = 0; ni < 2; ++ni)
                        acc[mi][ni] = __builtin_amdgcn_mfma_f32_16x16x32_bf16(a[mi], b[kk][ni], acc[mi][ni], 0, 0, 0);
            }
            __syncthreads();   // As+dloc fully consumed; scatter below uses registers only

            // scatter C fragments into LDS accumulator (ds_add_f32)
#pragma unroll
            for (int mi = 0; mi < 4; ++mi) {
#pragma unroll
                for (int reg = 0; reg < 4; ++reg) {
                    int d = dreg[mi][reg];
                    if (d >= 0) {
#pragma unroll
                        for (int ni = 0; ni < 2; ++ni)
                            atomicAdd(&outAcc[d * OPAD + nq + ni * 16 + lr], acc[mi][ni][reg]);
                    }
                }
            }
        }
    }
    __syncthreads();

    // epilogue: relu + store
    for (int idx = tid; idx < TROWS * 32; idx += 256) {
        int row = idx >> 5, n0 = (idx & 31) << 2;
        int g = row0 + row;
        if (g >= M) continue;
        f32x4 v = *(f32x4*)&outAcc[row * OPAD + n0];
        f32x4 o;
#pragma unroll
        for (int j = 0; j < 4; ++j) o[j] = v[j] > 0.f ? v[j] : 0.f;
        if (FINAL) {
            *(f32x4*)((float*)outv + (size_t)g * HDIM + n0) = o;
        } else {
            s16x4 ob;
#pragma unroll
            for (int j = 0; j < 4; ++j) ob[j] = f2bf(o[j]);
            *(s16x4*)((short*)outv + (size_t)g * HDIM + n0) = ob;
        }
    }
}

extern "C" void kernel_launch(void* const* d_in, const int* in_sizes, int n_in,
                              void* d_out, int out_size, void* d_ws, size_t ws_size,
                              hipStream_t stream) {
    const float* emb    = (const float*)d_in[0];
    const float* basis1 = (const float*)d_in[1];
    const float* wc1    = (const float*)d_in[2];
    const float* lw1    = (const float*)d_in[3];
    const float* bias1  = (const float*)d_in[4];
    const float* basis2 = (const float*)d_in[5];
    const float* wc2    = (const float*)d_in[6];
    const float* lw2    = (const float*)d_in[7];
    const float* bias2  = (const float*)d_in[8];
    const int* src = (const int*)d_in[9];
    const int* dst = (const int*)d_in[10];
    const int* rel = (const int*)d_in[11];

    int n_ent = in_sizes[0] / HDIM;
    int n_edges = in_sizes[9];
    int ntiles = (n_ent + TROWS - 1) / TROWS;   // 782
    int nb = ntiles * NREL;                     // 12512 buckets

    char* ws = (char*)d_ws;
    short* wtA = (short*)ws;                              // 557 KB
    short* wtB = wtA + 17 * HDIM * HDIM;                  // 557 KB
    short* h0  = wtB + 17 * HDIM * HDIM;                  // 12.8 MB bf16
    short* h1  = h0 + (size_t)n_ent * HDIM;               // 12.8 MB bf16
    int* src_s = (int*)(h1 + (size_t)n_ent * HDIM);       // 3.2 MB
    int* dst_s = src_s + n_edges;                         // 3.2 MB
    int* blockCnt = dst_s + n_edges;                      // 6.4 MB
    int* baseArr  = blockCnt + (size_t)HB * nb;           // 6.4 MB
    int* bucketOff = baseArr + (size_t)HB * nb;           // (nb+1)*4
    int* colsum    = bucketOff + nb + 1;                  // nb*4

    int chunk = (n_edges + HB - 1) / HB;

    compute_wt<<<NREL * HDIM, HDIM, 0, stream>>>(basis1, wc1, wtA);
    compute_wt<<<NREL * HDIM, HDIM, 0, stream>>>(basis2, wc2, wtB);
    transposeLW<<<HDIM, HDIM, 0, stream>>>(lw1, wtA + 16 * HDIM * HDIM);
    transposeLW<<<HDIM, HDIM, 0, stream>>>(lw2, wtB + 16 * HDIM * HDIM);
    cast_bf16<<<512, 256, 0, stream>>>(emb, h0, n_ent * HDIM / 4);

    histB<<<HB, 256, nb * 4, stream>>>(dst, rel, n_edges, chunk, nb, blockCnt);
    scanA<<<(nb + 255) / 256, 256, 0, stream>>>(blockCnt, baseArr, colsum, nb);
    scanB<<<1, 256, 0, stream>>>(colsum, bucketOff, nb);
    scatterB<<<HB, 256, nb * 4, stream>>>(src, dst, rel, n_edges, chunk, nb,
                                          bucketOff, baseArr, src_s, dst_s);

    node_gemm<0><<<ntiles, 256, 0, stream>>>(h0, wtA, bias1, bucketOff, src_s, dst_s, h1, n_ent);
    node_gemm<1><<<ntiles, 256, 0, stream>>>(h1, wtB, bias2, bucketOff, src_s, dst_s, d_out, n_ent);
}

// Round 9
// 953.996 us; speedup vs baseline: 2.2360x; 1.8946x over previous
//
#include <hip/hip_runtime.h>
#include <hip/hip_bf16.h>

#define HDIM 128
#define NREL 16
#define NBASES 8
#define LDSPAD 136      // 128+8 shorts: rows 16B-aligned, 2-way bank alias (free per m136)
#define SBLK 512        // counting-sort chunks

typedef short bf16x8 __attribute__((ext_vector_type(8)));
typedef short s16x4 __attribute__((ext_vector_type(4)));
typedef short s16x2 __attribute__((ext_vector_type(2)));
typedef float f32x4 __attribute__((ext_vector_type(4)));

static __device__ __forceinline__ short f2bf(float x) {
    __hip_bfloat16 b = __float2bfloat16(x);
    return *(short*)&b;
}
static __device__ __forceinline__ float bf2f(short s) {
    unsigned u = ((unsigned)(unsigned short)s) << 16;
    return *(float*)&u;
}

// packed bf16x2 atomic add -> global_atomic_pk_add_bf16 on gfx950
static __device__ __forceinline__ void atomic_add_bf162(short* addr, short lo, short hi) {
    s16x2 v; v[0] = lo; v[1] = hi;
#if __has_builtin(__builtin_amdgcn_flat_atomic_fadd_v2bf16)
    __builtin_amdgcn_flat_atomic_fadd_v2bf16((s16x2*)addr, v);
#elif __has_builtin(__builtin_amdgcn_global_atomic_fadd_v2bf16)
    typedef __attribute__((address_space(1))) s16x2 gs16x2;
    __builtin_amdgcn_global_atomic_fadd_v2bf16((gs16x2*)addr, v);
#else
    unsigned* ua = (unsigned*)addr;
    unsigned old = *ua, assumed;
    do {
        assumed = old;
        float f0 = bf2f((short)(assumed & 0xffff)) + bf2f(lo);
        float f1 = bf2f((short)(assumed >> 16)) + bf2f(hi);
        unsigned nv = ((unsigned)(unsigned short)f2bf(f1) << 16) | (unsigned short)f2bf(f0);
        old = atomicCAS(ua, assumed, nv);
    } while (old != assumed);
#endif
}

// ---------------- weight prep (fp32 in -> bf16 out) ----------------
// wt[r][o][i] = W_r[i][o] = sum_b wcomp[r][b] * basis[b][i][o]
__global__ void compute_wt(const float* __restrict__ basis,
                           const float* __restrict__ wcomp,
                           short* __restrict__ wt) {
    int ro = blockIdx.x;
    int r = ro >> 7, o = ro & 127;
    int i = threadIdx.x;
    float acc = 0.f;
#pragma unroll
    for (int b = 0; b < NBASES; ++b)
        acc += wcomp[r * NBASES + b] * basis[(b * HDIM + i) * HDIM + o];
    wt[(size_t)(r * HDIM + o) * HDIM + i] = f2bf(acc);
}

// lwT[o][i] = loop_w[i][o]
__global__ void transpose128(const float* __restrict__ in, short* __restrict__ out) {
    int o = blockIdx.x, i = threadIdx.x;
    out[o * HDIM + i] = f2bf(in[i * HDIM + o]);
}

__global__ void cast_bf16(const float* __restrict__ in, short* __restrict__ out, int n4) {
    for (int i = blockIdx.x * blockDim.x + threadIdx.x; i < n4; i += gridDim.x * blockDim.x) {
        f32x4 v = ((const f32x4*)in)[i];
        s16x4 o;
#pragma unroll
        for (int j = 0; j < 4; ++j) o[j] = f2bf(v[j]);
        ((s16x4*)out)[i] = o;
    }
}

// ---------------- counting sort by rel (contention-free, round-4 proven) ----------------
__global__ __launch_bounds__(256) void hist2(const int* __restrict__ rel, int n, int chunk,
                                             int* __restrict__ blockCnt) {
    __shared__ int h[NREL];
    int tid = threadIdx.x, b = blockIdx.x;
    if (tid < NREL) h[tid] = 0;
    __syncthreads();
    int lo = b * chunk, hi = min(n, lo + chunk);
    for (int e = lo + tid; e < hi; e += 256) atomicAdd(&h[rel[e]], 1);
    __syncthreads();
    if (tid < NREL) blockCnt[b * NREL + tid] = h[tid];
}

// meta ints: [16..32] offs, [49..65] tileOff, [66] ntiles
__global__ void scan2(const int* __restrict__ blockCnt, int* __restrict__ base,
                      int* __restrict__ meta) {
    __shared__ int tot[NREL];
    int t = threadIdx.x;
    if (t < NREL) {
        int run = 0;
        for (int b = 0; b < SBLK; ++b) {
            base[b * NREL + t] = run;
            run += blockCnt[b * NREL + t];
        }
        tot[t] = run;
    }
    __syncthreads();
    if (t == 0) {
        int* offs = meta + 16;
        int* tileOff = meta + 49;
        int o = 0, tl = 0;
        for (int r = 0; r < NREL; ++r) {
            offs[r] = o; tileOff[r] = tl;
            o += tot[r];
            tl += (tot[r] + 127) >> 7;
        }
        offs[NREL] = o;
        tileOff[NREL] = tl;
        meta[66] = tl;
    }
    __syncthreads();
    if (t < NREL) {
        int off = meta[16 + t];
        for (int b = 0; b < SBLK; ++b) base[b * NREL + t] += off;
    }
}

__global__ __launch_bounds__(256) void scatter2(const int* __restrict__ src,
                                                const int* __restrict__ dst,
                                                const int* __restrict__ rel, int n, int chunk,
                                                const int* __restrict__ base,
                                                int* __restrict__ src_s, int* __restrict__ dst_s) {
    __shared__ int cur[NREL];
    int tid = threadIdx.x, b = blockIdx.x;
    if (tid < NREL) cur[tid] = base[b * NREL + tid];
    __syncthreads();
    int lo = b * chunk, hi = min(n, lo + chunk);
    for (int e = lo + tid; e < hi; e += 256) {
        int r = rel[e];
        int p = atomicAdd(&cur[r], 1);
        src_s[p] = src[e];
        dst_s[p] = dst[e];
    }
}

// ---------------- self-loop GEMM: acc_bf16 = bf16(h @ loop_w + bias) ----------------
__global__ __launch_bounds__(256) void self_gemm(
    const short* __restrict__ h,    // bf16 [M,128]
    const short* __restrict__ bT,   // bf16 [o][i]
    const float* __restrict__ bias, // fp32 [128]
    short* __restrict__ out, int M) {   // bf16 accumulator [M,128]
    __shared__ short As[128 * LDSPAD];
    int tid = threadIdx.x;
    int row0 = blockIdx.x * 128;
    int wave = tid >> 6, lane = tid & 63;
    int mq = (wave & 1) * 64, nq = (wave >> 1) * 64;
    int lr = lane & 15, quad = lane >> 4;

    bf16x8 b[4][4];
#pragma unroll
    for (int kk = 0; kk < 4; ++kk)
#pragma unroll
        for (int ni = 0; ni < 4; ++ni)
            b[kk][ni] = *(const bf16x8*)(bT + (nq + ni * 16 + lr) * HDIM + kk * 32 + quad * 8);

    int lane16 = tid & 15, rsub = tid >> 4;
#pragma unroll
    for (int p = 0; p < 8; ++p) {
        int row = p * 16 + rsub;
        int g = row0 + row;
        bf16x8 va = (bf16x8)0;
        if (g < M) va = *(const bf16x8*)(h + (size_t)g * HDIM + lane16 * 8);
        *(bf16x8*)(As + row * LDSPAD + lane16 * 8) = va;
    }
    __syncthreads();

    f32x4 acc[4][4] = {};
#pragma unroll
    for (int kk = 0; kk < 4; ++kk) {
        int kb = kk * 32 + quad * 8;
        bf16x8 a[4];
#pragma unroll
        for (int mi = 0; mi < 4; ++mi)
            a[mi] = *(const bf16x8*)(As + (mq + mi * 16 + lr) * LDSPAD + kb);
#pragma unroll
        for (int mi = 0; mi < 4; ++mi)
#pragma unroll
            for (int ni = 0; ni < 4; ++ni)
                acc[mi][ni] = __builtin_amdgcn_mfma_f32_16x16x32_bf16(a[mi], b[kk][ni], acc[mi][ni], 0, 0, 0);
    }
    // pair-pack epilogue: lanes 2j/2j+1 exchange; even lane stores rows 0-1, odd rows 2-3
    int odd = lane & 1;
    int r0 = odd ? 2 : 0;
#pragma unroll
    for (int mi = 0; mi < 4; ++mi) {
#pragma unroll
        for (int ni = 0; ni < 4; ++ni) {
            f32x4 v = acc[mi][ni];
            f32x4 o;
#pragma unroll
            for (int j = 0; j < 4; ++j) o[j] = __shfl_xor(v[j], 1);
            int cb = nq + ni * 16 + (lr & ~1);
#pragma unroll
            for (int k = 0; k < 2; ++k) {
                int r = r0 + k;
                int g = row0 + mq + mi * 16 + quad * 4 + r;
                if (g < M) {
                    float e = (odd ? o[r] : v[r]) + bias[cb];       // col cb
                    float f = (odd ? v[r] : o[r]) + bias[cb + 1];   // col cb+1
                    s16x2 p;
                    p[0] = f2bf(e);
                    p[1] = f2bf(f);
                    *(s16x2*)(out + (size_t)g * HDIM + cb) = p;
                }
            }
        }
    }
}

// ---------------- edge GEMM: acc_bf16[dst] += h[src] @ W_r (packed bf16 atomics) ----------------
__global__ __launch_bounds__(256) void edge_gemm(
    const short* __restrict__ h,
    const short* __restrict__ wt,   // bf16 [16][o][i]
    const int* __restrict__ meta,
    const int* __restrict__ src_s, const int* __restrict__ dst_s,
    short* __restrict__ out) {      // bf16 accumulator
    int t = blockIdx.x;
    if (t >= meta[66]) return;
    const int* offs = meta + 16;
    const int* tileOff = meta + 49;
    int r = 0;
    while (r < NREL - 1 && t >= tileOff[r + 1]) ++r;
    int e0 = offs[r] + (t - tileOff[r]) * 128;
    int eEnd = offs[r + 1];

    __shared__ short As[128 * LDSPAD];
    __shared__ int dloc[128];
    int tid = threadIdx.x;
    int wave = tid >> 6, lane = tid & 63;
    int mq = (wave & 1) * 64, nq = (wave >> 1) * 64;
    int lr = lane & 15, quad = lane >> 4;

    const short* wr = wt + (size_t)r * HDIM * HDIM;
    bf16x8 b[4][4];
#pragma unroll
    for (int kk = 0; kk < 4; ++kk)
#pragma unroll
        for (int ni = 0; ni < 4; ++ni)
            b[kk][ni] = *(const bf16x8*)(wr + (nq + ni * 16 + lr) * HDIM + kk * 32 + quad * 8);

    int lane16 = tid & 15, rsub = tid >> 4;
#pragma unroll
    for (int p = 0; p < 8; ++p) {
        int row = p * 16 + rsub;
        int e = e0 + row;
        bf16x8 va = (bf16x8)0;
        if (e < eEnd) {
            int s = src_s[e];
            va = *(const bf16x8*)(h + (size_t)s * HDIM + lane16 * 8);
        }
        *(bf16x8*)(As + row * LDSPAD + lane16 * 8) = va;
    }
    if (tid < 128) {
        int e = e0 + tid;
        dloc[tid] = (e < eEnd) ? dst_s[e] : -1;
    }
    __syncthreads();

    f32x4 acc[4][4] = {};
#pragma unroll
    for (int kk = 0; kk < 4; ++kk) {
        int kb = kk * 32 + quad * 8;
        bf16x8 a[4];
#pragma unroll
        for (int mi = 0; mi < 4; ++mi)
            a[mi] = *(const bf16x8*)(As + (mq + mi * 16 + lr) * LDSPAD + kb);
#pragma unroll
        for (int mi = 0; mi < 4; ++mi)
#pragma unroll
            for (int ni = 0; ni < 4; ++ni)
                acc[mi][ni] = __builtin_amdgcn_mfma_f32_16x16x32_bf16(a[mi], b[kk][ni], acc[mi][ni], 0, 0, 0);
    }
    // pair-pack epilogue with packed bf16 atomics (single chunk per block: dloc is stable)
    int odd = lane & 1;
    int r0 = odd ? 2 : 0;
#pragma unroll
    for (int mi = 0; mi < 4; ++mi) {
#pragma unroll
        for (int ni = 0; ni < 4; ++ni) {
            f32x4 v = acc[mi][ni];
            f32x4 o;
#pragma unroll
            for (int j = 0; j < 4; ++j) o[j] = __shfl_xor(v[j], 1);
            int cb = nq + ni * 16 + (lr & ~1);
#pragma unroll
            for (int k = 0; k < 2; ++k) {
                int r2 = r0 + k;
                int m = mq + mi * 16 + quad * 4 + r2;
                int d = dloc[m];
                if (d >= 0) {
                    short plo = f2bf(odd ? o[r2] : v[r2]);   // col cb
                    short phi = f2bf(odd ? v[r2] : o[r2]);   // col cb+1
                    atomic_add_bf162(out + (size_t)d * HDIM + cb, plo, phi);
                }
            }
        }
    }
}

// ---------------- finalize: relu on bf16 accumulator ----------------
__global__ void finalize_relu_bb(const short* __restrict__ in, short* __restrict__ out, int n4) {
    for (int i = blockIdx.x * blockDim.x + threadIdx.x; i < n4; i += gridDim.x * blockDim.x) {
        s16x4 v = ((const s16x4*)in)[i];
        s16x4 o;
#pragma unroll
        for (int j = 0; j < 4; ++j) o[j] = (v[j] < 0) ? (short)0 : v[j];  // sign bit => negative bf16
        ((s16x4*)out)[i] = o;
    }
}

__global__ void finalize_relu_bf(const short* __restrict__ in, float* __restrict__ out, int n4) {
    for (int i = blockIdx.x * blockDim.x + threadIdx.x; i < n4; i += gridDim.x * blockDim.x) {
        s16x4 v = ((const s16x4*)in)[i];
        f32x4 o;
#pragma unroll
        for (int j = 0; j < 4; ++j) {
            float x = bf2f(v[j]);
            o[j] = x > 0.f ? x : 0.f;
        }
        ((f32x4*)out)[i] = o;
    }
}

extern "C" void kernel_launch(void* const* d_in, const int* in_sizes, int n_in,
                              void* d_out, int out_size, void* d_ws, size_t ws_size,
                              hipStream_t stream) {
    const float* emb    = (const float*)d_in[0];
    const float* basis1 = (const float*)d_in[1];
    const float* wc1    = (const float*)d_in[2];
    const float* lw1    = (const float*)d_in[3];
    const float* bias1  = (const float*)d_in[4];
    const float* basis2 = (const float*)d_in[5];
    const float* wc2    = (const float*)d_in[6];
    const float* lw2    = (const float*)d_in[7];
    const float* bias2  = (const float*)d_in[8];
    const int* src = (const int*)d_in[9];
    const int* dst = (const int*)d_in[10];
    const int* rel = (const int*)d_in[11];

    int n_ent = in_sizes[0] / HDIM;
    int n_edges = in_sizes[9];

    char* ws = (char*)d_ws;
    int* meta = (int*)ws;                            // 1 KB
    short* wt1  = (short*)(ws + 1024);               // 512 KB bf16
    short* wt2  = wt1 + NREL * HDIM * HDIM;          // 512 KB
    short* lw1T = wt2 + NREL * HDIM * HDIM;          // 32 KB
    short* lw2T = lw1T + HDIM * HDIM;                // 32 KB
    short* h0   = lw2T + HDIM * HDIM;                // 12.8 MB bf16
    short* h1   = h0 + (size_t)n_ent * HDIM;         // 12.8 MB bf16
    short* accb = h1 + (size_t)n_ent * HDIM;         // 12.8 MB bf16 accumulator
    int* src_s  = (int*)(accb + (size_t)n_ent * HDIM); // 3.2 MB
    int* dst_s  = src_s + n_edges;                   // 3.2 MB
    int* blockCnt = dst_s + n_edges;                 // 32 KB
    int* baseArr  = blockCnt + SBLK * NREL;          // 32 KB

    int chunk = (n_edges + SBLK - 1) / SBLK;

    compute_wt<<<NREL * HDIM, HDIM, 0, stream>>>(basis1, wc1, wt1);
    compute_wt<<<NREL * HDIM, HDIM, 0, stream>>>(basis2, wc2, wt2);
    transpose128<<<HDIM, HDIM, 0, stream>>>(lw1, lw1T);
    transpose128<<<HDIM, HDIM, 0, stream>>>(lw2, lw2T);
    cast_bf16<<<512, 256, 0, stream>>>(emb, h0, n_ent * HDIM / 4);

    hist2<<<SBLK, 256, 0, stream>>>(rel, n_edges, chunk, blockCnt);
    scan2<<<1, 64, 0, stream>>>(blockCnt, baseArr, meta);
    scatter2<<<SBLK, 256, 0, stream>>>(src, dst, rel, n_edges, chunk, baseArr, src_s, dst_s);

    int mtiles = (n_ent + 127) / 128;
    int etiles = (n_edges + 127) / 128 + NREL;

    // layer 1
    self_gemm<<<mtiles, 256, 0, stream>>>(h0, lw1T, bias1, accb, n_ent);
    edge_gemm<<<etiles, 256, 0, stream>>>(h0, wt1, meta, src_s, dst_s, accb);
    finalize_relu_bb<<<512, 256, 0, stream>>>(accb, h1, n_ent * HDIM / 4);

    // layer 2
    self_gemm<<<mtiles, 256, 0, stream>>>(h1, lw2T, bias2, accb, n_ent);
    edge_gemm<<<etiles, 256, 0, stream>>>(h1, wt2, meta, src_s, dst_s, accb);
    finalize_relu_bf<<<512, 256, 0, stream>>>(accb, (float*)d_out, n_ent * HDIM / 4);
}